// Round 4
// baseline (60.248 us; speedup 1.0000x reference)
//
#include <hip/hip_runtime.h>
#include <stdint.h>

typedef _Float16 f16;
typedef _Float16 f16x8 __attribute__((ext_vector_type(8)));
typedef _Float16 f16x4 __attribute__((ext_vector_type(4)));
typedef float f32x4 __attribute__((ext_vector_type(4)));

#define D_DIM 4096
#define H_DIM 256
#define E_DIM 64
#define BM 32
#define BK 64
#define KSPLIT 4
#define NKT2 16   // K-steps per split slice: 1024/64

// ---- merged pack: w1 [4096][256] -> w1s fragment order; w2 [256][64] -> w2s ----
// w1s f16 index: ((kt*16 + c16)*2 + kk)*512 + lane*8 + j
//   = w1[(kt*64 + kk*32 + (lane>>4)*8 + j)][c16*16 + (lane&15)]
// w2s f16 index: (cg*8 + ks)*512 + lane*8 + j = w2[ks*32+(lane>>4)*8+j][cg*16+(lane&15)]
__global__ void pack_kernel(const float* __restrict__ w1, f16* __restrict__ w1s,
                            const float* __restrict__ w2, f16* __restrict__ w2s) {
  const int b = blockIdx.x;
  const int t = threadIdx.x;
  if (b < 512) {
    const int u = b * 256 + t;
    const int lane = u & 63;
    const int kk = (u >> 6) & 1;
    const int c16 = (u >> 7) & 15;
    const int kt = u >> 11;
    const int g = lane >> 4, r = lane & 15;
    const int k0 = kt * 64 + kk * 32 + g * 8;
    const int col = c16 * 16 + r;
    f16x8 o;
#pragma unroll
    for (int j = 0; j < 8; ++j) o[j] = (f16)w1[(size_t)(k0 + j) * H_DIM + col];
    *(f16x8*)(w1s + (size_t)u * 8) = o;
  } else {
    const int u = (b - 512) * 256 + t;
    const int lane = u & 63;
    const int ks = (u >> 6) & 7;
    const int cg = u >> 9;
    const int g = lane >> 4, r = lane & 15;
    const int k0 = ks * 32 + g * 8;
    const int col = cg * 16 + r;
    f16x8 o;
#pragma unroll
    for (int j = 0; j < 8; ++j) o[j] = (f16)w2[(size_t)(k0 + j) * E_DIM + col];
    *(f16x8*)(w2s + (size_t)u * 8) = o;
  }
}

// ---- GEMM1 split-K: partial[rb*4+ks][32][256] = x[rb*32:, ks*1024:] @ w1[ks*1024:,:] ----
// grid 1024 (4 blocks/CU), 512 thr (8 waves). ks = bid&3 so co-resident blocks share slice.
__launch_bounds__(512)
__global__ void gemm1_splitk_kernel(const float* __restrict__ x,
                                    const f16* __restrict__ w1s,
                                    float* __restrict__ hpart) {
  __shared__ __align__(16) f16 As0[BM * BK];
  __shared__ __align__(16) f16 As1[BM * BK];

  const int t = threadIdx.x;
  const int lane = t & 63;
  const int wn = t >> 6;
  const int g = lane >> 4, r = lane & 15;
  const int bid = blockIdx.x;
  const int ks = bid & 3;
  const int rb = bid >> 2;
  const int brow = rb * BM;

  const int a_row = t >> 4;
  const int a_col = (t & 15) << 2;
  const int a_sw = a_col ^ ((a_row & 7) << 3);
  const float* xrow = x + (size_t)(brow + a_row) * D_DIM + ks * 1024 + a_col;
  const f16* bptr = w1s + (size_t)ks * 16 * 16384 + (size_t)(wn * 2) * 1024 + lane * 8;

  f32x4 acc[2][2] = {{{0.f,0.f,0.f,0.f},{0.f,0.f,0.f,0.f}},
                     {{0.f,0.f,0.f,0.f},{0.f,0.f,0.f,0.f}}};
  f16x8 B0[4], B1[4];
  float4 xE, xO;

#define LDX(kt) (*(const float4*)(xrow + (kt) * 64))
#define LDB(kt, B)                                                  \
  {                                                                 \
    const f16* p_ = bptr + (size_t)(kt) * 16384;                    \
    (B)[0] = *(const f16x8*)(p_);                                   \
    (B)[1] = *(const f16x8*)(p_ + 512);                             \
    (B)[2] = *(const f16x8*)(p_ + 1024);                            \
    (B)[3] = *(const f16x8*)(p_ + 1536);                            \
  }
#define STW(As, v)                                                  \
  {                                                                 \
    f16x4 hv_;                                                      \
    hv_[0] = (f16)(v).x; hv_[1] = (f16)(v).y;                       \
    hv_[2] = (f16)(v).z; hv_[3] = (f16)(v).w;                       \
    *(f16x4*)((As) + a_row * 64 + a_sw) = hv_;                      \
  }
#define COMP(As, B)                                                            \
  {                                                                            \
    _Pragma("unroll") for (int kk = 0; kk < 2; ++kk) {                         \
      const int kb_ = kk * 32 + g * 8;                                         \
      _Pragma("unroll") for (int rh = 0; rh < 2; ++rh) {                       \
        const int arow_ = rh * 16 + r;                                         \
        const f16x8 af_ =                                                      \
            *(const f16x8*)((As) + arow_ * 64 + (kb_ ^ ((arow_ & 7) << 3)));   \
        _Pragma("unroll") for (int ch = 0; ch < 2; ++ch) {                     \
          acc[rh][ch] = __builtin_amdgcn_mfma_f32_16x16x32_f16(                \
              af_, (B)[kk + ch * 2], acc[rh][ch], 0, 0, 0);                    \
        }                                                                      \
      }                                                                        \
    }                                                                          \
  }
#define BAR()                                          \
  asm volatile("s_waitcnt lgkmcnt(0)" ::: "memory");   \
  __builtin_amdgcn_s_barrier();

  // prologue
  {
    float4 t0 = LDX(0);
    LDB(0, B0);
    LDB(1, B1);
    xE = LDX(1);
    xO = LDX(2);
    STW(As0, t0);
    BAR();
  }

#pragma unroll 1
  for (int s = 0; s < NKT2; s += 2) {
    STW(As1, xE);
    xE = LDX(s + 3 < NKT2 ? s + 3 : NKT2 - 1);
    COMP(As0, B0);
    LDB(s + 2 < NKT2 ? s + 2 : NKT2 - 1, B0);
    BAR();
    STW(As0, xO);
    xO = LDX(s + 4 < NKT2 ? s + 4 : NKT2 - 1);
    COMP(As1, B1);
    LDB(s + 3 < NKT2 ? s + 3 : NKT2 - 1, B1);
    BAR();
  }

  // store f32 partial [32][256]
  float* hp = hpart + (size_t)bid * (BM * H_DIM);
#pragma unroll
  for (int rh = 0; rh < 2; ++rh)
#pragma unroll
    for (int ch = 0; ch < 2; ++ch) {
      const int col = wn * 32 + ch * 16 + r;
#pragma unroll
      for (int j = 0; j < 4; ++j) {
        const int row = rh * 16 + g * 4 + j;
        hp[row * H_DIM + col] = acc[rh][ch][j];
      }
    }
}

// ---- reduce partials + bias + relu + gemm2 + sparsemax ----
// grid 256, 512 thr (8 waves)
__launch_bounds__(512)
__global__ void reduce_fused_kernel(const float* __restrict__ hpart,
                                    const float* __restrict__ b1,
                                    const f16* __restrict__ w2s,
                                    const float* __restrict__ b2,
                                    float* __restrict__ out) {
  __shared__ __align__(16) char smem[24576];
  f16* h_lds = (f16*)smem;                 // [32][256] f16 swizzled
  float* u_lds = (float*)(smem + 16384);   // [32][64]

  const int t = threadIdx.x;
  const int lane = t & 63;
  const int wn = t >> 6;
  const int g = lane >> 4, r = lane & 15;
  const int brow = blockIdx.x * BM;

  const float* base = hpart + (size_t)blockIdx.x * (KSPLIT * BM * H_DIM);
  float4 s[4];
#pragma unroll
  for (int i = 0; i < 4; ++i)
    s[i] = *(const float4*)(base + (size_t)(i * 512 + t) * 4);
#pragma unroll
  for (int c = 1; c < KSPLIT; ++c) {
    const float* cb = base + (size_t)c * (BM * H_DIM);
#pragma unroll
    for (int i = 0; i < 4; ++i) {
      const float4 v = *(const float4*)(cb + (size_t)(i * 512 + t) * 4);
      s[i].x += v.x; s[i].y += v.y; s[i].z += v.z; s[i].w += v.w;
    }
  }
#pragma unroll
  for (int i = 0; i < 4; ++i) {
    const int f = i * 512 + t;
    const int row = f >> 6;
    const int col = (f & 63) << 2;
    const float4 bv = *(const float4*)(b1 + col);
    f16x4 hv;
    hv[0] = (f16)fmaxf(s[i].x + bv.x, 0.f);
    hv[1] = (f16)fmaxf(s[i].y + bv.y, 0.f);
    hv[2] = (f16)fmaxf(s[i].z + bv.z, 0.f);
    hv[3] = (f16)fmaxf(s[i].w + bv.w, 0.f);
    *(f16x4*)(h_lds + row * 256 + (col ^ ((row & 7) << 3))) = hv;
  }
  __syncthreads();

  // gemm2: u = h @ w2 + b2 (one 16x16 tile per wave)
  const int rh2 = wn & 1;
  const int cg = wn >> 1;
  f32x4 acc2 = {0.f, 0.f, 0.f, 0.f};
  const f16* w2p = w2s + (size_t)(cg * 8) * 512 + lane * 8;
#pragma unroll
  for (int ksi = 0; ksi < 8; ++ksi) {
    const int arow = rh2 * 16 + r;
    const int kb = ksi * 32 + g * 8;
    const f16x8 af = *(const f16x8*)(h_lds + arow * 256 + (kb ^ ((arow & 7) << 3)));
    const f16x8 bf = *(const f16x8*)(w2p + ksi * 512);
    acc2 = __builtin_amdgcn_mfma_f32_16x16x32_f16(af, bf, acc2, 0, 0, 0);
  }
  {
    const int col = cg * 16 + r;
    const float bias = b2[col];
#pragma unroll
    for (int j = 0; j < 4; ++j) {
      const int row = rh2 * 16 + g * 4 + j;
      u_lds[row * 64 + col] = acc2[j] + bias;
    }
  }
  __syncthreads();

  // bisection sparsemax; 16 lanes/row, 4 vals/lane
  const int srow = wn * 4 + (lane >> 4);
  const int scol = (lane & 15) << 2;
  const float4 uv = *(const float4*)(u_lds + srow * 64 + scol);
  float u0 = uv.x, u1 = uv.y, u2 = uv.z, u3 = uv.w;

  float mx = fmaxf(fmaxf(u0, u1), fmaxf(u2, u3));
  float mn = fminf(fminf(u0, u1), fminf(u2, u3));
#pragma unroll
  for (int m = 1; m < 16; m <<= 1) {
    mx = fmaxf(mx, __shfl_xor(mx, m));
    mn = fminf(mn, __shfl_xor(mn, m));
  }
  float lo = mn - 10.0f, hi = mx;
#pragma unroll 1
  for (int it = 0; it < 32; ++it) {
    const float mid = 0.5f * (lo + hi);
    float sm = fmaxf(u0 - mid, 0.f) + fmaxf(u1 - mid, 0.f) +
               fmaxf(u2 - mid, 0.f) + fmaxf(u3 - mid, 0.f);
#pragma unroll
    for (int m = 1; m < 16; m <<= 1) sm += __shfl_xor(sm, m);
    const bool pos = (sm - 1.0f) > 0.0f;
    lo = pos ? mid : lo;
    hi = pos ? hi : mid;
  }
  const float tau = 0.5f * (lo + hi);
  const float p0 = fmaxf(u0 - tau, 0.f);
  const float p1 = fmaxf(u1 - tau, 0.f);
  const float p2 = fmaxf(u2 - tau, 0.f);
  const float p3 = fmaxf(u3 - tau, 0.f);
  float sum = p0 + p1 + p2 + p3;
#pragma unroll
  for (int m = 1; m < 16; m <<= 1) sum += __shfl_xor(sum, m);
  const float inv = 1.0f / (sum + 1e-8f);
  float4 pv;
  pv.x = p0 * inv; pv.y = p1 * inv; pv.z = p2 * inv; pv.w = p3 * inv;
  *(float4*)(out + (size_t)(brow + srow) * E_DIM + scol) = pv;
}

extern "C" void kernel_launch(void* const* d_in, const int* in_sizes, int n_in,
                              void* d_out, int out_size, void* d_ws, size_t ws_size,
                              hipStream_t stream) {
  const float* x  = (const float*)d_in[0];
  const float* w1 = (const float*)d_in[1];
  const float* b1 = (const float*)d_in[2];
  const float* w2 = (const float*)d_in[3];
  const float* b2 = (const float*)d_in[4];
  float* out = (float*)d_out;

  char* wsb = (char*)d_ws;
  f16* w1s = (f16*)wsb;                        // 2 MB
  f16* w2s = (f16*)(wsb + (2u << 20));         // 32 KB
  float* hpart = (float*)(wsb + (4u << 20));   // 1024*32*256 f32 = 32 MB

  pack_kernel<<<520, 256, 0, stream>>>(w1, w1s, w2, w2s);
  gemm1_splitk_kernel<<<1024, 512, 0, stream>>>(x, w1s, hpart);
  reduce_fused_kernel<<<256, 512, 0, stream>>>(hpart, b1, w2s, b2, out);
}

// Round 5
// 57.855 us; speedup vs baseline: 1.0414x; 1.0414x over previous
//
#include <hip/hip_runtime.h>
#include <stdint.h>

typedef _Float16 f16;
typedef _Float16 f16x8 __attribute__((ext_vector_type(8)));
typedef _Float16 f16x4 __attribute__((ext_vector_type(4)));
typedef float f32x4 __attribute__((ext_vector_type(4)));

#define D_DIM 4096
#define H_DIM 256
#define E_DIM 64
#define BM 128
#define BK 64
#define KSPLIT 4
#define NKT2 16                 // K-steps per slice: 1024/64
#define HP_SLICE (8192 * 256)   // f32 elems per hpart slice

// ---- merged pack: w1 [4096][256] -> w1s fragment order; w2 [256][64] -> w2s ----
// w1s f16 index: ((kt*16 + c16)*2 + kk)*512 + lane*8 + j
//   = w1[(kt*64 + kk*32 + (lane>>4)*8 + j)][c16*16 + (lane&15)]
__global__ void pack_kernel(const float* __restrict__ w1, f16* __restrict__ w1s,
                            const float* __restrict__ w2, f16* __restrict__ w2s) {
  const int b = blockIdx.x;
  const int t = threadIdx.x;
  if (b < 512) {
    const int u = b * 256 + t;
    const int lane = u & 63;
    const int kk = (u >> 6) & 1;
    const int c16 = (u >> 7) & 15;
    const int kt = u >> 11;
    const int g = lane >> 4, r = lane & 15;
    const int k0 = kt * 64 + kk * 32 + g * 8;
    const int col = c16 * 16 + r;
    f16x8 o;
#pragma unroll
    for (int j = 0; j < 8; ++j) o[j] = (f16)w1[(size_t)(k0 + j) * H_DIM + col];
    *(f16x8*)(w1s + (size_t)u * 8) = o;
  } else {
    const int u = (b - 512) * 256 + t;
    const int lane = u & 63;
    const int ks = (u >> 6) & 7;
    const int cg = u >> 9;
    const int g = lane >> 4, r = lane & 15;
    const int k0 = ks * 32 + g * 8;
    const int col = cg * 16 + r;
    f16x8 o;
#pragma unroll
    for (int j = 0; j < 8; ++j) o[j] = (f16)w2[(size_t)(k0 + j) * E_DIM + col];
    *(f16x8*)(w2s + (size_t)u * 8) = o;
  }
}

// ---- GEMM1 split-K, BM=128: hpart[ks][brow:brow+128][256] = x_slice @ w1_slice ----
// grid 256 (1/CU), 512 thr (8 waves, 2x4). ks=bid&3 -> one w1s slice per XCD L2.
__launch_bounds__(512, 2)
__global__ void gemm1_splitk_kernel(const float* __restrict__ x,
                                    const f16* __restrict__ w1s,
                                    float* __restrict__ hpart) {
  __shared__ __align__(16) f16 buf0[BM * BK];  // 16 KB
  __shared__ __align__(16) f16 buf1[BM * BK];  // 16 KB

  const int t = threadIdx.x;
  const int lane = t & 63;
  const int wn = t >> 6;
  const int wm = wn >> 2;       // 0..1  (row half: 64 rows)
  const int wc = wn & 3;        // 0..3  (col group: 64 cols)
  const int g = lane >> 4, r = lane & 15;
  const int bid = blockIdx.x;
  const int ks = bid & 3;
  const int brow = (bid >> 2) * BM;

  // x staging: 4 float4/thread/step; i-th covers row i*32 + (t>>4)
  const float* xb = x + (size_t)(brow + (t >> 4)) * D_DIM + ks * 1024 + ((t & 15) << 2);
  const int stw_swz = (((t & 15) << 2) ^ (((t >> 4) & 7) << 3));
  const int stw_row0 = (t >> 4);

  const f16* bptr = w1s + (size_t)ks * (16 * 16384) + (size_t)(wc * 8) * 512 + lane * 8;

  f32x4 acc[4][4];
#pragma unroll
  for (int mf = 0; mf < 4; ++mf)
#pragma unroll
    for (int nf = 0; nf < 4; ++nf) acc[mf][nf] = (f32x4){0.f, 0.f, 0.f, 0.f};

  f16x8 BE[8], BO[8];          // B frags [nf*2+kk]
  float4 xA[4], xB[4], xP[4];  // staged x (4 float4 each)

#define LDX(kt, xr)                                                     \
  {                                                                     \
    _Pragma("unroll") for (int i = 0; i < 4; ++i)                       \
      (xr)[i] = *(const float4*)(xb + (size_t)i * (32 * D_DIM) + (kt) * 64); \
  }
#define LDB(kt, B)                                                      \
  {                                                                     \
    const f16* p_ = bptr + (size_t)(kt) * 16384;                        \
    _Pragma("unroll") for (int q = 0; q < 8; ++q)                       \
      (B)[q] = *(const f16x8*)(p_ + q * 512);                           \
  }
#define STW(dst, xr)                                                    \
  {                                                                     \
    _Pragma("unroll") for (int i = 0; i < 4; ++i) {                     \
      f16x4 hv_;                                                        \
      hv_[0] = (f16)(xr)[i].x; hv_[1] = (f16)(xr)[i].y;                 \
      hv_[2] = (f16)(xr)[i].z; hv_[3] = (f16)(xr)[i].w;                 \
      *(f16x4*)((dst) + (i * 32 + stw_row0) * 64 + stw_swz) = hv_;      \
    }                                                                   \
  }
#define COMP(buf, B)                                                           \
  {                                                                            \
    _Pragma("unroll") for (int kk = 0; kk < 2; ++kk) {                         \
      const int kb_ = (kk * 32 + g * 8) ^ ((r & 7) << 3);                      \
      _Pragma("unroll") for (int mf = 0; mf < 4; ++mf) {                       \
        const int row_ = wm * 64 + mf * 16 + r;                                \
        const f16x8 af_ = *(const f16x8*)((buf) + row_ * 64 + kb_);            \
        _Pragma("unroll") for (int nf = 0; nf < 4; ++nf) {                     \
          acc[mf][nf] = __builtin_amdgcn_mfma_f32_16x16x32_f16(                \
              af_, (B)[nf * 2 + kk], acc[mf][nf], 0, 0, 0);                    \
        }                                                                      \
      }                                                                        \
    }                                                                          \
  }
#define BAR()                                          \
  asm volatile("s_waitcnt lgkmcnt(0)" ::: "memory");   \
  __builtin_amdgcn_s_barrier();

  // prologue: buf0 = A(0); BE=B(0); BO=B(1); xA=x(1); xB=x(2)
  {
    LDX(0, xP);
    LDB(0, BE);
    LDB(1, BO);
    LDX(1, xA);
    LDX(2, xB);
    STW(buf0, xP);
    BAR();
  }

#pragma unroll 1
  for (int it = 0; it < NKT2 / 2; ++it) {
    const int kt = it * 2;
    // even step kt: compute buf0/BE
    STW(buf1, xA);
    {
      int sx = kt + 3; if (sx > NKT2 - 1) sx = NKT2 - 1;
      LDX(sx, xA);
    }
    COMP(buf0, BE);
    {
      int sb = kt + 2; if (sb > NKT2 - 1) sb = NKT2 - 1;
      LDB(sb, BE);
    }
    BAR();
    // odd step kt+1: compute buf1/BO
    STW(buf0, xB);
    {
      int sx = kt + 4; if (sx > NKT2 - 1) sx = NKT2 - 1;
      LDX(sx, xB);
    }
    COMP(buf1, BO);
    {
      int sb = kt + 3; if (sb > NKT2 - 1) sb = NKT2 - 1;
      LDB(sb, BO);
    }
    BAR();
  }

  // store f32 partials: hpart[ks][brow+row][col]
  float* hp = hpart + (size_t)ks * HP_SLICE + (size_t)brow * H_DIM;
#pragma unroll
  for (int mf = 0; mf < 4; ++mf)
#pragma unroll
    for (int nf = 0; nf < 4; ++nf) {
      const int col = wc * 64 + nf * 16 + r;
#pragma unroll
      for (int j = 0; j < 4; ++j) {
        const int row = wm * 64 + mf * 16 + g * 4 + j;
        hp[(size_t)row * H_DIM + col] = acc[mf][nf][j];
      }
    }
}

// ---- reduce partials + bias + relu + gemm2 + sparsemax (32 rows/block) ----
__launch_bounds__(512)
__global__ void reduce_fused_kernel(const float* __restrict__ hpart,
                                    const float* __restrict__ b1,
                                    const f16* __restrict__ w2s,
                                    const float* __restrict__ b2,
                                    float* __restrict__ out) {
  __shared__ __align__(16) char smem[24576];
  f16* h_lds = (f16*)smem;                 // [32][256] f16 swizzled
  float* u_lds = (float*)(smem + 16384);   // [32][64]

  const int t = threadIdx.x;
  const int lane = t & 63;
  const int wn = t >> 6;
  const int g = lane >> 4, r = lane & 15;
  const int brow = blockIdx.x * 32;

  const float* base = hpart + (size_t)brow * H_DIM;
  float4 s[4];
#pragma unroll
  for (int i = 0; i < 4; ++i)
    s[i] = *(const float4*)(base + (size_t)(i * 512 + t) * 4);
#pragma unroll
  for (int c = 1; c < KSPLIT; ++c) {
    const float* cb = base + (size_t)c * HP_SLICE;
#pragma unroll
    for (int i = 0; i < 4; ++i) {
      const float4 v = *(const float4*)(cb + (size_t)(i * 512 + t) * 4);
      s[i].x += v.x; s[i].y += v.y; s[i].z += v.z; s[i].w += v.w;
    }
  }
#pragma unroll
  for (int i = 0; i < 4; ++i) {
    const int f = i * 512 + t;
    const int row = f >> 6;
    const int col = (f & 63) << 2;
    const float4 bv = *(const float4*)(b1 + col);
    f16x4 hv;
    hv[0] = (f16)fmaxf(s[i].x + bv.x, 0.f);
    hv[1] = (f16)fmaxf(s[i].y + bv.y, 0.f);
    hv[2] = (f16)fmaxf(s[i].z + bv.z, 0.f);
    hv[3] = (f16)fmaxf(s[i].w + bv.w, 0.f);
    *(f16x4*)(h_lds + row * 256 + (col ^ ((row & 7) << 3))) = hv;
  }
  __syncthreads();

  // gemm2: u = h @ w2 + b2 (one 16x16 tile per wave)
  const int rh2 = wn & 1;
  const int cg = wn >> 1;
  f32x4 acc2 = {0.f, 0.f, 0.f, 0.f};
  const f16* w2p = w2s + (size_t)(cg * 8) * 512 + lane * 8;
#pragma unroll
  for (int ksi = 0; ksi < 8; ++ksi) {
    const int arow = rh2 * 16 + r;
    const int kb = ksi * 32 + g * 8;
    const f16x8 af = *(const f16x8*)(h_lds + arow * 256 + (kb ^ ((arow & 7) << 3)));
    const f16x8 bf = *(const f16x8*)(w2p + ksi * 512);
    acc2 = __builtin_amdgcn_mfma_f32_16x16x32_f16(af, bf, acc2, 0, 0, 0);
  }
  {
    const int col = cg * 16 + r;
    const float bias = b2[col];
#pragma unroll
    for (int j = 0; j < 4; ++j) {
      const int row = rh2 * 16 + g * 4 + j;
      u_lds[row * 64 + col] = acc2[j] + bias;
    }
  }
  __syncthreads();

  // bisection sparsemax; 16 lanes/row, 4 vals/lane
  const int srow = wn * 4 + (lane >> 4);
  const int scol = (lane & 15) << 2;
  const float4 uv = *(const float4*)(u_lds + srow * 64 + scol);
  float u0 = uv.x, u1 = uv.y, u2 = uv.z, u3 = uv.w;

  float mx = fmaxf(fmaxf(u0, u1), fmaxf(u2, u3));
  float mn = fminf(fminf(u0, u1), fminf(u2, u3));
#pragma unroll
  for (int m = 1; m < 16; m <<= 1) {
    mx = fmaxf(mx, __shfl_xor(mx, m));
    mn = fminf(mn, __shfl_xor(mn, m));
  }
  float lo = mn - 10.0f, hi = mx;
#pragma unroll 1
  for (int it = 0; it < 32; ++it) {
    const float mid = 0.5f * (lo + hi);
    float sm = fmaxf(u0 - mid, 0.f) + fmaxf(u1 - mid, 0.f) +
               fmaxf(u2 - mid, 0.f) + fmaxf(u3 - mid, 0.f);
#pragma unroll
    for (int m = 1; m < 16; m <<= 1) sm += __shfl_xor(sm, m);
    const bool pos = (sm - 1.0f) > 0.0f;
    lo = pos ? mid : lo;
    hi = pos ? hi : mid;
  }
  const float tau = 0.5f * (lo + hi);
  const float p0 = fmaxf(u0 - tau, 0.f);
  const float p1 = fmaxf(u1 - tau, 0.f);
  const float p2 = fmaxf(u2 - tau, 0.f);
  const float p3 = fmaxf(u3 - tau, 0.f);
  float sum = p0 + p1 + p2 + p3;
#pragma unroll
  for (int m = 1; m < 16; m <<= 1) sum += __shfl_xor(sum, m);
  const float inv = 1.0f / (sum + 1e-8f);
  float4 pv;
  pv.x = p0 * inv; pv.y = p1 * inv; pv.z = p2 * inv; pv.w = p3 * inv;
  *(float4*)(out + (size_t)(brow + srow) * E_DIM + scol) = pv;
}

extern "C" void kernel_launch(void* const* d_in, const int* in_sizes, int n_in,
                              void* d_out, int out_size, void* d_ws, size_t ws_size,
                              hipStream_t stream) {
  const float* x  = (const float*)d_in[0];
  const float* w1 = (const float*)d_in[1];
  const float* b1 = (const float*)d_in[2];
  const float* w2 = (const float*)d_in[3];
  const float* b2 = (const float*)d_in[4];
  float* out = (float*)d_out;

  char* wsb = (char*)d_ws;
  f16* w1s = (f16*)wsb;                        // 2 MB
  f16* w2s = (f16*)(wsb + (2u << 20));         // 32 KB
  float* hpart = (float*)(wsb + (4u << 20));   // 4*8192*256 f32 = 32 MB

  pack_kernel<<<520, 256, 0, stream>>>(w1, w1s, w2, w2s);
  gemm1_splitk_kernel<<<256, 512, 0, stream>>>(x, w1s, hpart);
  reduce_fused_kernel<<<256, 512, 0, stream>>>(hpart, b1, w2s, b2, out);
}